// Round 3
// baseline (254.109 us; speedup 1.0000x reference)
//
#include <hip/hip_runtime.h>
#include <math.h>

#define G 2
#define BB 2
#define L 1024
#define DM 256
#define DI 512
#define DS 16
#define DR 16
#define CH 64              // chunks per sequence
#define CL 16              // L / CH
#define RTOT (G*BB*L)      // 4096 rows per layer-step
#define YSTR 520           // Ys LDS row stride (shorts)
#define XSTR 520           // xc LDS row stride (shorts)

typedef short bh8 __attribute__((ext_vector_type(8)));
typedef float f4x __attribute__((ext_vector_type(4)));

#define MFMA16 __builtin_amdgcn_mfma_f32_16x16x32_bf16

__device__ __forceinline__ float silu_f(float x) { return x / (1.f + __expf(-x)); }
__device__ __forceinline__ float softplus_f(float x) {
    return (x > 20.f) ? x : __logf(1.f + __expf(x));
}

__device__ __forceinline__ unsigned short f2bf(float f) {
    unsigned u = __float_as_uint(f);
    unsigned r = u + 0x7FFFu + ((u >> 16) & 1u);
    return (unsigned short)(r >> 16);
}
__device__ __forceinline__ float bf2f(unsigned short s) {
    return __uint_as_float(((unsigned)s) << 16);
}
__device__ __forceinline__ void split4s(float4 v, short4& h, short4& l) {
    unsigned short s;
    s = f2bf(v.x); h.x = (short)s; l.x = (short)f2bf(v.x - bf2f(s));
    s = f2bf(v.y); h.y = (short)s; l.y = (short)f2bf(v.y - bf2f(s));
    s = f2bf(v.z); h.z = (short)s; l.z = (short)f2bf(v.z - bf2f(s));
    s = f2bf(v.w); h.w = (short)s; l.w = (short)f2bf(v.w - bf2f(s));
}
__device__ __forceinline__ void split8(float4 v0, float4 v1, bh8& h, bh8& l) {
    float f[8] = {v0.x, v0.y, v0.z, v0.w, v1.x, v1.y, v1.z, v1.w};
    #pragma unroll
    for (int j = 0; j < 8; j++) {
        unsigned short s = f2bf(f[j]);
        h[j] = (short)s;
        l[j] = (short)f2bf(f[j] - bf2f(s));
    }
}

// ---------------------------------------------------------------------------
// megaA: per (gb, chunk) block computes EVERYTHING up to the chunk scan:
//   in_proj GEMM for its 32-row A-tile (16 real rows + 3 halo + 13 pad)
//   -> xc-half to LDS, z-half to Zb global
//   -> depthwise conv + silu (XCb side-write)
//   -> x_proj 3xbf16 MFMA (dbl, DBLc side-write)
//   -> dt + chunk-local scan (Aprod/Hend).
// All weights read fp32 and split to bf16 hi/lo on the fly (traffic-neutral).
// LDS plan (73008 B total, two overlaid phases):
//   phase1: Ah[32*264]s @0, Al @16896, xz[19][516]f @33792
//   phase2: xcH[16*520]s @0, xcL @16640, part[8][16][48]f @33792, dbl @58368
// ---------------------------------------------------------------------------
template<int AMAP>
__global__ __launch_bounds__(512) void megaA(
    const float* __restrict__ Ax,
    const short* __restrict__ APh, const short* __restrict__ APl,
    const float* __restrict__ Win, const float* __restrict__ cw,
    const float* __restrict__ cb, const float* __restrict__ Wx,
    const float* __restrict__ A_log, const float* __restrict__ Wdt,
    const float* __restrict__ bdt,
    float* __restrict__ XCb, float* __restrict__ Zb, float* __restrict__ DBLc,
    float* __restrict__ Aprod, float* __restrict__ Hend, int step)
{
    __shared__ __align__(16) char smem[73008];
    short* Ah  = (short*)smem;
    short* Al  = (short*)(smem + 16896);
    float* xz  = (float*)(smem + 33792);    // [19][516]
    short* xcH = (short*)smem;              // phase2 overlay
    short* xcL = (short*)(smem + 16640);
    float* part = (float*)(smem + 33792);   // [8][16][48]
    float* dbl  = (float*)(smem + 58368);   // [16][48]

    const int blk = blockIdx.x;
    const int c   = blk & (CH - 1);
    const int gb  = blk >> 6;
    const int g   = gb >> 1;
    const int lay = g * 2 + step;
    const int tid = threadIdx.x;
    const int r0  = gb * L + c * CL;
    const int lane = tid & 63, wv = tid >> 6;
    const int m = lane & 15, quad = lane >> 4;

    // ---- stage A-tile: 32 rows (r0-16 .. r0+15) x 256 k, bf16 hi/lo ----
    #pragma unroll
    for (int i = 0; i < 4; i++) {
        int id = tid + 512 * i;          // 0..2047 = 32 rows x 64 float4
        int row = id >> 6, kq = id & 63;
        int gr  = r0 - 16 + row;
        int grc = (gr < gb * L) ? gb * L : gr;   // clamp; masked later
        if (AMAP == 1) {
            int b = (grc >> 10) & 1, l = grc & 1023;
            int sl = g ? (1023 - l) : l;
            float4 v = *(const float4*)&Ax[(size_t)(b * 1024 + sl) * DM + kq * 4];
            short4 h4, l4; split4s(v, h4, l4);
            *(short4*)&Ah[row * 264 + kq * 4] = h4;
            *(short4*)&Al[row * 264 + kq * 4] = l4;
        } else {
            size_t o = (size_t)grc * DM + kq * 4;
            *(short4*)&Ah[row * 264 + kq * 4] = *(const short4*)&APh[o];
            *(short4*)&Al[row * 264 + kq * 4] = *(const short4*)&APl[o];
        }
    }
    __syncthreads();

    // ---- in_proj GEMM: A(32x256) @ Win^T(1024x256), B streamed from L2 ----
    const float* Wg = Win + (size_t)lay * 1024 * DM;
    #pragma unroll
    for (int ct = 0; ct < 2; ct++) {
        const int colb = ct * 512 + wv * 64;
        const int mt0 = ct;              // z-half needs only rows 16..31
        f4x acc[2][4] = {};
        for (int kt = 0; kt < 8; kt++) {
            const int kb = kt * 32 + quad * 8;
            bh8 ahf[2], alf[2];
            #pragma unroll
            for (int mt = 0; mt < 2; mt++) {
                if (mt < mt0) continue;
                ahf[mt] = *(bh8*)&Ah[(mt * 16 + m) * 264 + kb];
                alf[mt] = *(bh8*)&Al[(mt * 16 + m) * 264 + kb];
            }
            float4 braw[4][2];
            #pragma unroll
            for (int nt = 0; nt < 4; nt++) {
                const float* bp = &Wg[(size_t)(colb + nt * 16 + m) * DM + kb];
                braw[nt][0] = *(const float4*)bp;
                braw[nt][1] = *(const float4*)(bp + 4);
            }
            #pragma unroll
            for (int nt = 0; nt < 4; nt++) {
                bh8 bh, bl; split8(braw[nt][0], braw[nt][1], bh, bl);
                #pragma unroll
                for (int mt = 0; mt < 2; mt++) {
                    if (mt < mt0) continue;
                    acc[mt][nt] = MFMA16(ahf[mt], bh, acc[mt][nt], 0, 0, 0);
                    acc[mt][nt] = MFMA16(ahf[mt], bl, acc[mt][nt], 0, 0, 0);
                    acc[mt][nt] = MFMA16(alf[mt], bh, acc[mt][nt], 0, 0, 0);
                }
            }
        }
        #pragma unroll
        for (int nt = 0; nt < 4; nt++) {
            int gcol = colb + nt * 16 + m;
            #pragma unroll
            for (int mt = 0; mt < 2; mt++) {
                if (mt < mt0) continue;
                #pragma unroll
                for (int r = 0; r < 4; r++) {
                    int i = mt * 16 + quad * 4 + r;     // local A row
                    float v = acc[mt][nt][r];
                    if (ct == 0) {
                        if (i >= 13) xz[(i - 13) * 516 + gcol] = v;
                    } else {
                        if (i >= 16)
                            Zb[(size_t)(r0 + i - 16) * 512 + (gcol - 512)] = v;
                    }
                }
            }
        }
    }
    __syncthreads();

    // ---- depthwise conv + silu (channel d = tid) ----
    const int d = tid;
    float4 w4 = *(const float4*)&cw[((size_t)lay * DI + d) * 4];
    float cbv = cb[(size_t)lay * DI + d];
    float xzv[CL + 3];
    #pragma unroll
    for (int j = 0; j < CL + 3; j++)
        xzv[j] = (c * CL + j - 3 < 0) ? 0.f : xz[j * 516 + d];
    float xc[CL];
    #pragma unroll
    for (int tt = 0; tt < CL; tt++) {
        float v = cbv + w4.x * xzv[tt] + w4.y * xzv[tt + 1]
                      + w4.z * xzv[tt + 2] + w4.w * xzv[tt + 3];
        v = silu_f(v);
        xc[tt] = v;
        XCb[(size_t)(r0 + tt) * DI + d] = v;
        unsigned short hs = f2bf(v);
        xcH[tt * XSTR + d] = (short)hs;
        xcL[tt * XSTR + d] = (short)f2bf(v - bf2f(hs));
    }
    __syncthreads();

    // ---- x_proj: dbl[16][48] = xc @ Wx^T, 3xbf16 MFMA, split-K=64/wave ----
    {
        const int ks = wv * 64;
        const float* Wxg = Wx + (size_t)lay * 48 * DI;
        f4x acc3[3] = {};
        #pragma unroll
        for (int kt = 0; kt < 2; kt++) {
            const int kb = ks + kt * 32 + quad * 8;
            bh8 ah = *(bh8*)&xcH[m * XSTR + kb];
            bh8 al = *(bh8*)&xcL[m * XSTR + kb];
            #pragma unroll
            for (int f = 0; f < 3; f++) {
                const float* wp = &Wxg[(size_t)(f * 16 + m) * DI + kb];
                bh8 bh, bl;
                split8(*(const float4*)wp, *(const float4*)(wp + 4), bh, bl);
                acc3[f] = MFMA16(ah, bh, acc3[f], 0, 0, 0);
                acc3[f] = MFMA16(ah, bl, acc3[f], 0, 0, 0);
                acc3[f] = MFMA16(al, bh, acc3[f], 0, 0, 0);
            }
        }
        #pragma unroll
        for (int f = 0; f < 3; f++)
            #pragma unroll
            for (int r = 0; r < 4; r++)
                part[(wv * 16 + quad * 4 + r) * 48 + f * 16 + m] = acc3[f][r];
    }
    __syncthreads();

    for (int o = d; o < CL * 48; o += 512) {
        int tt = o / 48, cc = o - tt * 48;
        float v = 0.f;
        #pragma unroll
        for (int w = 0; w < 8; w++) v += part[(w * 16 + tt) * 48 + cc];
        dbl[tt * 48 + cc] = v;
        DBLc[(size_t)(r0 + tt) * 48 + cc] = v;   // compact side-write for scanB
    }

    // ---- dt + chunk-local scan ----
    float wdt[16];
    const float* wrow = Wdt + ((size_t)lay * DI + d) * DR;
    #pragma unroll
    for (int k = 0; k < 16; k += 4) {
        float4 v = *(const float4*)&wrow[k];
        wdt[k] = v.x; wdt[k + 1] = v.y; wdt[k + 2] = v.z; wdt[k + 3] = v.w;
    }
    float bias = bdt[(size_t)lay * DI + d];

    float a[DS], h[DS], ap[DS];
    const float* al = A_log + ((size_t)lay * DI + d) * DS;
    #pragma unroll
    for (int s = 0; s < DS; s++) { a[s] = -__expf(al[s]); h[s] = 0.f; ap[s] = 1.f; }
    __syncthreads();

    for (int tt = 0; tt < CL; tt++) {
        float dtr = bias;
        #pragma unroll
        for (int k = 0; k < 16; k++) dtr += dbl[tt * 48 + k] * wdt[k];
        float dt = softplus_f(dtr);
        float dx = dt * xc[tt];
        #pragma unroll
        for (int s = 0; s < DS; s++) {
            float da = __expf(dt * a[s]);
            h[s] = da * h[s] + dx * dbl[tt * 48 + 16 + s];
            ap[s] *= da;
        }
    }
    size_t base = ((size_t)(gb * DI + d) * CH + c) * DS;
    #pragma unroll
    for (int q = 0; q < 4; q++) {
        *(float4*)&Aprod[base + q * 4] = make_float4(ap[q*4], ap[q*4+1], ap[q*4+2], ap[q*4+3]);
        *(float4*)&Hend [base + q * 4] = make_float4(h[q*4],  h[q*4+1],  h[q*4+2],  h[q*4+3]);
    }
}

// ---------------------------------------------------------------------------
// Combine: serial exclusive scan over CH chunks per (gb,d,s) lane. (unchanged)
// ---------------------------------------------------------------------------
__global__ __launch_bounds__(256) void scanCombine(
    const float* __restrict__ Aprod, const float* __restrict__ Hend,
    float* __restrict__ Hinit)
{
    int idx = blockIdx.x * 256 + threadIdx.x;  // (gb*DI+d)*DS + s
    int s  = idx & 15;
    int gd = idx >> 4;
    size_t base = (size_t)gd * CH * DS + s;
    float h = 0.f;
    for (int c0 = 0; c0 < CH; c0 += 8) {
        float ap[8], e[8];
        #pragma unroll
        for (int j = 0; j < 8; j++) {
            size_t o = base + (size_t)(c0 + j) * DS;
            ap[j] = Aprod[o]; e[j] = Hend[o];
        }
        #pragma unroll
        for (int j = 0; j < 8; j++) {
            Hinit[base + (size_t)(c0 + j) * DS] = h;
            h = ap[j] * h + e[j];
        }
    }
}

// ---------------------------------------------------------------------------
// Scan phase B + FUSED out_proj. Wout read fp32, split on the fly.
// z read from compact Zb. OUTMODE 0: Pout bf16 hi/lo pairs; 1: fp32 scatter.
// ---------------------------------------------------------------------------
template<int OUTMODE>
__global__ __launch_bounds__(512) void scanB_fused(
    const float* __restrict__ XCb, const float* __restrict__ DBLc,
    const float* __restrict__ Zb, const float* __restrict__ A_log,
    const float* __restrict__ Wdt, const float* __restrict__ bdt,
    const float* __restrict__ Dp, const float* __restrict__ Hinit,
    const float* __restrict__ Wout,
    float* __restrict__ Cout, short* __restrict__ Ph, short* __restrict__ Pl,
    int step)
{
    __shared__ float dbl[CL][48];
    __shared__ short Ys_hi[CL * YSTR];
    __shared__ short Ys_lo[CL * YSTR];
    int blk = blockIdx.x;
    int c  = blk & (CH - 1);
    int gb = blk >> 6;
    int g  = gb >> 1;
    int lay = g * 2 + step;
    int d = threadIdx.x;
    int r0 = gb * L + c * CL;

    for (int id = threadIdx.x; id < CL * 48; id += 512) {
        int rr = id / 48, cc = id - rr * 48;
        dbl[rr][cc] = DBLc[(size_t)(r0 + rr) * 48 + cc];
    }

    float xc[CL], zz[CL];
    #pragma unroll
    for (int tt = 0; tt < CL; tt++) xc[tt] = XCb[(size_t)(r0 + tt) * DI + d];
    #pragma unroll
    for (int tt = 0; tt < CL; tt++) zz[tt] = Zb[(size_t)(r0 + tt) * 512 + d];

    float wdt[16];
    const float* wrow = Wdt + ((size_t)lay * DI + d) * DR;
    #pragma unroll
    for (int k = 0; k < 16; k += 4) {
        float4 v = *(const float4*)&wrow[k];
        wdt[k] = v.x; wdt[k + 1] = v.y; wdt[k + 2] = v.z; wdt[k + 3] = v.w;
    }
    float bias = bdt[(size_t)lay * DI + d];

    float a[DS], h[DS];
    const float* al = A_log + ((size_t)lay * DI + d) * DS;
    size_t base = ((size_t)(gb * DI + d) * CH + c) * DS;
    #pragma unroll
    for (int q = 0; q < 4; q++) {
        float4 hv = *(const float4*)&Hinit[base + q * 4];
        h[q*4] = hv.x; h[q*4+1] = hv.y; h[q*4+2] = hv.z; h[q*4+3] = hv.w;
    }
    #pragma unroll
    for (int s = 0; s < DS; s++) a[s] = -__expf(al[s]);
    float Dv = Dp[(size_t)lay * DI + d];
    __syncthreads();

    #pragma unroll
    for (int tt = 0; tt < CL; tt++) {
        float dtr = bias;
        #pragma unroll
        for (int k = 0; k < 16; k++) dtr += dbl[tt][k] * wdt[k];
        float dt = softplus_f(dtr);
        float dx = dt * xc[tt];
        float y = 0.f;
        #pragma unroll
        for (int s = 0; s < DS; s++) {
            float da = __expf(dt * a[s]);
            h[s] = da * h[s] + dx * dbl[tt][16 + s];
            y += h[s] * dbl[tt][32 + s];
        }
        y += xc[tt] * Dv;
        y *= silu_f(zz[tt]);
        unsigned short hs = f2bf(y);
        Ys_hi[tt * YSTR + d] = (short)hs;
        Ys_lo[tt * YSTR + d] = (short)f2bf(y - bf2f(hs));
    }
    __syncthreads();

    // ---- fused out_proj epilogue: 16 rows x 256 cols, K=512 ----
    const int lane = threadIdx.x & 63, wv = threadIdx.x >> 6;
    const int m = lane & 15, quad = lane >> 4;
    const float* Wog = Wout + (size_t)lay * DM * DI;

    #pragma unroll
    for (int q = 0; q < 2; q++) {
        const int coln = wv * 32 + q * 16 + m;
        const float* wrp = &Wog[(size_t)coln * DI];
        bh8 wh[16], wl[16];
        #pragma unroll
        for (int i = 0; i < 16; i++) {
            const float* p = wrp + i * 32 + quad * 8;
            split8(*(const float4*)p, *(const float4*)(p + 4), wh[i], wl[i]);
        }
        f4x acc = {};
        #pragma unroll
        for (int i = 0; i < 16; i++) {
            const int kk = i * 32 + quad * 8;
            bh8 ahv = *(bh8*)&Ys_hi[m * YSTR + kk];
            bh8 alv = *(bh8*)&Ys_lo[m * YSTR + kk];
            acc = MFMA16(ahv, wh[i], acc, 0, 0, 0);
            acc = MFMA16(ahv, wl[i], acc, 0, 0, 0);
            acc = MFMA16(alv, wh[i], acc, 0, 0, 0);
        }
        #pragma unroll
        for (int r = 0; r < 4; r++) {
            int tt = quad * 4 + r;
            int grow = r0 + tt;
            if (OUTMODE == 0) {
                size_t o = (size_t)grow * DM + coln;
                unsigned short hs = f2bf(acc[r]);
                Ph[o] = (short)hs;
                Pl[o] = (short)f2bf(acc[r] - bf2f(hs));
            } else {
                int b = (grow >> 10) & 1, l = grow & 1023;
                size_t dst = (g == 0)
                    ? ((size_t)(b * 1024 + l) * 512 + coln)
                    : ((size_t)(b * 1024 + (1023 - l)) * 512 + 256 + coln);
                Cout[dst] = acc[r];
            }
        }
    }
}

extern "C" void kernel_launch(void* const* d_in, const int* in_sizes, int n_in,
                              void* d_out, int out_size, void* d_ws, size_t ws_size,
                              hipStream_t stream)
{
    const float* x        = (const float*)d_in[0];
    const float* in_proj  = (const float*)d_in[1];
    const float* conv_w   = (const float*)d_in[2];
    const float* conv_b   = (const float*)d_in[3];
    const float* x_proj   = (const float*)d_in[4];
    const float* dt_proj  = (const float*)d_in[5];
    const float* dt_bias  = (const float*)d_in[6];
    const float* A_log    = (const float*)d_in[7];
    const float* Dp       = (const float*)d_in[8];
    const float* out_proj = (const float*)d_in[9];
    float* out = (float*)d_out;

    float* w = (float*)d_ws;
    size_t o = 0;
    float* XCb   = w + o; o += (size_t)RTOT * DI;
    float* Zb    = w + o; o += (size_t)RTOT * 512;
    float* DBLc  = w + o; o += (size_t)RTOT * 48;
    float* Aprod = w + o; o += (size_t)G * BB * DI * CH * DS;
    float* Hend  = w + o; o += (size_t)G * BB * DI * CH * DS;
    float* Hinit = w + o; o += (size_t)G * BB * DI * CH * DS;
    short* Ph    = (short*)(w + o); o += (size_t)RTOT * DM / 2;
    short* Pl    = (short*)(w + o); o += (size_t)RTOT * DM / 2;
    (void)ws_size; (void)in_sizes; (void)n_in; (void)out_size;

    for (int step = 0; step < 2; step++) {
        // fused in_proj + conv + x_proj + dt + chunk scan: 256 blocks.
        if (step == 0)
            megaA<1><<<G * BB * CH, 512, 0, stream>>>(
                x, nullptr, nullptr, in_proj, conv_w, conv_b, x_proj,
                A_log, dt_proj, dt_bias, XCb, Zb, DBLc, Aprod, Hend, 0);
        else
            megaA<0><<<G * BB * CH, 512, 0, stream>>>(
                nullptr, Ph, Pl, in_proj, conv_w, conv_b, x_proj,
                A_log, dt_proj, dt_bias, XCb, Zb, DBLc, Aprod, Hend, 1);

        scanCombine<<<(G * BB * DI * DS) / 256, 256, 0, stream>>>(Aprod, Hend, Hinit);

        if (step == 0)
            scanB_fused<0><<<G * BB * CH, 512, 0, stream>>>(
                XCb, DBLc, Zb, A_log, dt_proj, dt_bias, Dp, Hinit,
                out_proj, nullptr, Ph, Pl, 0);
        else
            scanB_fused<1><<<G * BB * CH, 512, 0, stream>>>(
                XCb, DBLc, Zb, A_log, dt_proj, dt_bias, Dp, Hinit,
                out_proj, out, nullptr, nullptr, 1);
    }
}

// Round 4
// 230.764 us; speedup vs baseline: 1.1012x; 1.1012x over previous
//
#include <hip/hip_runtime.h>
#include <math.h>

#define G 2
#define BB 2
#define L 1024
#define DM 256
#define DI 512
#define DS 16
#define DR 16
#define CH 64              // chunks per sequence
#define CL 16              // L / CH
#define RTOT (G*BB*L)      // 4096 rows per layer-step
#define YSTR 520           // Ys LDS row stride (shorts)
#define XSTR 520           // xc LDS row stride (shorts)

typedef short bh8 __attribute__((ext_vector_type(8)));
typedef float f4x __attribute__((ext_vector_type(4)));

#define MFMA16 __builtin_amdgcn_mfma_f32_16x16x32_bf16

__device__ __forceinline__ float silu_f(float x) { return x / (1.f + __expf(-x)); }
__device__ __forceinline__ float softplus_f(float x) {
    return (x > 20.f) ? x : __logf(1.f + __expf(x));
}

__device__ __forceinline__ unsigned short f2bf(float f) {
    unsigned u = __float_as_uint(f);
    unsigned r = u + 0x7FFFu + ((u >> 16) & 1u);
    return (unsigned short)(r >> 16);
}
__device__ __forceinline__ float bf2f(unsigned short s) {
    return __uint_as_float(((unsigned)s) << 16);
}
__device__ __forceinline__ void split4s(float4 v, short4& h, short4& l) {
    unsigned short s;
    s = f2bf(v.x); h.x = (short)s; l.x = (short)f2bf(v.x - bf2f(s));
    s = f2bf(v.y); h.y = (short)s; l.y = (short)f2bf(v.y - bf2f(s));
    s = f2bf(v.z); h.z = (short)s; l.z = (short)f2bf(v.z - bf2f(s));
    s = f2bf(v.w); h.w = (short)s; l.w = (short)f2bf(v.w - bf2f(s));
}
__device__ __forceinline__ void split8(float4 v0, float4 v1, bh8& h, bh8& l) {
    float f[8] = {v0.x, v0.y, v0.z, v0.w, v1.x, v1.y, v1.z, v1.w};
    #pragma unroll
    for (int j = 0; j < 8; j++) {
        unsigned short s = f2bf(f[j]);
        h[j] = (short)s;
        l[j] = (short)f2bf(f[j] - bf2f(s));
    }
}

// ---------------------------------------------------------------------------
// in_proj MFMA GEMM (3xbf16). BM=128, BN=128, K=256. grid (8,32) = 256 blocks.
// W read fp32, split to bf16 hi/lo during LDS staging (per-block tile only:
// 128x32 per k-step -> ~100 VALU/iter, hidden under MFMA).
// AMAP 1: A = x (fp32) with g-dependent time reversal (step 0).
// AMAP 0: A = Pout as pre-split bf16 hi/lo (step 1).
// ---------------------------------------------------------------------------
template<int AMAP>
__global__ __launch_bounds__(256) void mfma_inproj(
    const float* __restrict__ Ax,
    const short* __restrict__ APh, const short* __restrict__ APl,
    const float* __restrict__ Win,
    int step, float* __restrict__ C)
{
    constexpr int Ktot = DM, ldc = 1024;
    __shared__ short As_hi[128 * 40];
    __shared__ short As_lo[128 * 40];
    __shared__ short Bs_hi[128 * 40];
    __shared__ short Bs_lo[128 * 40];

    const int row0 = blockIdx.y * 128;
    const int col0 = blockIdx.x * 128;
    const int g    = row0 >> 11;
    const int lay  = g * 2 + step;
    const float* Wg = Win + (size_t)lay * 1024 * Ktot;
    const int t    = threadIdx.x;
    const int lane = t & 63, wv = t >> 6;
    const int m = lane & 15, quad = lane >> 4;
    const int wr = wv >> 1, wc = wv & 1;
    const int NT = Ktot / 32;     // 8

    float4 pa[4];
    short4 pah[4], pal[4];
    float4 pb[4];
    auto loadT = [&](int kt) {
        const int kb = kt * 32;
        #pragma unroll
        for (int i = 0; i < 4; i++) {
            int id = t + 256 * i;          // 0..1023 = 128 rows x 8 float4
            int row = id >> 3, kq = id & 7;
            if (AMAP == 1) {
                int gr = row0 + row;
                int gg = gr >> 11, b = (gr >> 10) & 1, l = gr & 1023;
                int sl = gg ? (1023 - l) : l;
                pa[i] = *(const float4*)&Ax[(size_t)(b * 1024 + sl) * Ktot + kb + kq * 4];
            } else {
                size_t o = (size_t)(row0 + row) * Ktot + kb + kq * 4;
                pah[i] = *(const short4*)&APh[o];
                pal[i] = *(const short4*)&APl[o];
            }
            pb[i] = *(const float4*)&Wg[(size_t)(col0 + row) * Ktot + kb + kq * 4];
        }
    };

    f4x acc[4][4] = {};
    loadT(0);

    for (int kt = 0; kt < NT; kt++) {
        #pragma unroll
        for (int i = 0; i < 4; i++) {
            int id = t + 256 * i;
            int row = id >> 3, kq = id & 7;
            if (AMAP == 1) {
                short4 h4, l4; split4s(pa[i], h4, l4);
                *(short4*)&As_hi[row * 40 + kq * 4] = h4;
                *(short4*)&As_lo[row * 40 + kq * 4] = l4;
            } else {
                *(short4*)&As_hi[row * 40 + kq * 4] = pah[i];
                *(short4*)&As_lo[row * 40 + kq * 4] = pal[i];
            }
            short4 h4, l4; split4s(pb[i], h4, l4);
            *(short4*)&Bs_hi[row * 40 + kq * 4] = h4;
            *(short4*)&Bs_lo[row * 40 + kq * 4] = l4;
        }
        __syncthreads();
        if (kt + 1 < NT) loadT(kt + 1);

        bh8 ah[4], al[4], bh[4], bl[4];
        #pragma unroll
        for (int p = 0; p < 4; p++) {
            int r = wr * 64 + p * 16 + m;
            ah[p] = *(bh8*)&As_hi[r * 40 + quad * 8];
            al[p] = *(bh8*)&As_lo[r * 40 + quad * 8];
        }
        #pragma unroll
        for (int q = 0; q < 4; q++) {
            int r = wc * 64 + q * 16 + m;
            bh[q] = *(bh8*)&Bs_hi[r * 40 + quad * 8];
            bl[q] = *(bh8*)&Bs_lo[r * 40 + quad * 8];
        }
        #pragma unroll
        for (int p = 0; p < 4; p++)
            #pragma unroll
            for (int q = 0; q < 4; q++) {
                acc[p][q] = MFMA16(ah[p], bh[q], acc[p][q], 0, 0, 0);
                acc[p][q] = MFMA16(ah[p], bl[q], acc[p][q], 0, 0, 0);
                acc[p][q] = MFMA16(al[p], bh[q], acc[p][q], 0, 0, 0);
            }
        __syncthreads();
    }

    #pragma unroll
    for (int p = 0; p < 4; p++)
        #pragma unroll
        for (int q = 0; q < 4; q++) {
            int gcol = col0 + wc * 64 + q * 16 + m;
            #pragma unroll
            for (int r = 0; r < 4; r++) {
                int grow = row0 + wr * 64 + p * 16 + quad * 4 + r;
                C[(size_t)grow * ldc + gcol] = acc[p][q][r];
            }
        }
}

// ---------------------------------------------------------------------------
// scanA2: conv+silu + x_proj GEMM (3xbf16 MFMA, split-K over 8 waves) + dt +
// chunk-local scan, one block per (gb, chunk). Wx read fp32, split on the fly
// (48 elems/lane). No XCb side-write (scanB recomputes conv).
// ---------------------------------------------------------------------------
__global__ __launch_bounds__(512) void scanA2(
    const float* __restrict__ XZ, const float* __restrict__ cw,
    const float* __restrict__ cb, const float* __restrict__ Wx,
    const float* __restrict__ A_log, const float* __restrict__ Wdt,
    const float* __restrict__ bdt,
    float* __restrict__ DBLc,
    float* __restrict__ Aprod, float* __restrict__ Hend, int step)
{
    __shared__ short xcH[CL * XSTR];
    __shared__ short xcL[CL * XSTR];
    __shared__ float part[8][CL][48];
    __shared__ float dbl[CL][48];

    const int blk = blockIdx.x;
    const int c  = blk & (CH - 1);
    const int gb = blk >> 6;
    const int g  = gb >> 1;
    const int lay = g * 2 + step;
    const int d  = threadIdx.x;          // channel 0..511
    const int r0 = gb * L + c * CL;

    // ---- depthwise conv + silu for channel d, rows r0..r0+CL-1 ----
    float4 w4 = *(const float4*)&cw[((size_t)lay * DI + d) * 4];
    float cbv = cb[(size_t)lay * DI + d];
    float xz[CL + 3];
    #pragma unroll
    for (int j = 0; j < CL + 3; j++) {
        int lr = c * CL + j - 3;                  // local row in sequence
        xz[j] = (lr < 0) ? 0.f : XZ[(size_t)(gb * L + lr) * 1024 + d];
    }
    float xc[CL];
    #pragma unroll
    for (int tt = 0; tt < CL; tt++) {
        float v = cbv + w4.x * xz[tt] + w4.y * xz[tt + 1]
                      + w4.z * xz[tt + 2] + w4.w * xz[tt + 3];
        v = silu_f(v);
        xc[tt] = v;
        unsigned short hs = f2bf(v);
        xcH[tt * XSTR + d] = (short)hs;
        xcL[tt * XSTR + d] = (short)f2bf(v - bf2f(hs));
    }
    __syncthreads();

    // ---- dbl[16][48] = xc[16][512] @ Wx^T : 3xbf16 MFMA, split-K=64/wave ----
    {
        const int lane = d & 63, wv = d >> 6;
        const int m = lane & 15, quad = lane >> 4;
        const int ks = wv * 64;
        const float* Wxg = Wx + (size_t)lay * 48 * DI;
        f4x acc3[3] = {};
        #pragma unroll
        for (int kt = 0; kt < 2; kt++) {
            const int kb = ks + kt * 32 + quad * 8;
            bh8 ah = *(bh8*)&xcH[m * XSTR + kb];
            bh8 al = *(bh8*)&xcL[m * XSTR + kb];
            #pragma unroll
            for (int f = 0; f < 3; f++) {
                const float* wp = &Wxg[(size_t)(f * 16 + m) * DI + kb];
                bh8 bh, bl;
                split8(*(const float4*)wp, *(const float4*)(wp + 4), bh, bl);
                acc3[f] = MFMA16(ah, bh, acc3[f], 0, 0, 0);
                acc3[f] = MFMA16(ah, bl, acc3[f], 0, 0, 0);
                acc3[f] = MFMA16(al, bh, acc3[f], 0, 0, 0);
            }
        }
        #pragma unroll
        for (int f = 0; f < 3; f++)
            #pragma unroll
            for (int r = 0; r < 4; r++)
                part[wv][quad * 4 + r][f * 16 + m] = acc3[f][r];
    }
    __syncthreads();

    for (int o = d; o < CL * 48; o += 512) {
        int tt = o / 48, cc = o - tt * 48;
        float v = 0.f;
        #pragma unroll
        for (int w = 0; w < 8; w++) v += part[w][tt][cc];
        dbl[tt][cc] = v;
        DBLc[(size_t)(r0 + tt) * 48 + cc] = v;    // compact side-write for scanB
    }

    // ---- dt + chunk-local scan ----
    float wdt[16];
    const float* wrow = Wdt + ((size_t)lay * DI + d) * DR;
    #pragma unroll
    for (int k = 0; k < 16; k += 4) {
        float4 v = *(const float4*)&wrow[k];
        wdt[k] = v.x; wdt[k + 1] = v.y; wdt[k + 2] = v.z; wdt[k + 3] = v.w;
    }
    float bias = bdt[(size_t)lay * DI + d];

    float a[DS], h[DS], ap[DS];
    const float* al = A_log + ((size_t)lay * DI + d) * DS;
    #pragma unroll
    for (int s = 0; s < DS; s++) { a[s] = -__expf(al[s]); h[s] = 0.f; ap[s] = 1.f; }
    __syncthreads();

    for (int tt = 0; tt < CL; tt++) {
        float dtr = bias;
        #pragma unroll
        for (int k = 0; k < 16; k++) dtr += dbl[tt][k] * wdt[k];
        float dt = softplus_f(dtr);
        float dx = dt * xc[tt];
        #pragma unroll
        for (int s = 0; s < DS; s++) {
            float da = __expf(dt * a[s]);
            h[s] = da * h[s] + dx * dbl[tt][16 + s];
            ap[s] *= da;
        }
    }
    size_t base = ((size_t)(gb * DI + d) * CH + c) * DS;
    #pragma unroll
    for (int q = 0; q < 4; q++) {
        *(float4*)&Aprod[base + q * 4] = make_float4(ap[q*4], ap[q*4+1], ap[q*4+2], ap[q*4+3]);
        *(float4*)&Hend [base + q * 4] = make_float4(h[q*4],  h[q*4+1],  h[q*4+2],  h[q*4+3]);
    }
}

// ---------------------------------------------------------------------------
// Combine: serial exclusive scan over CH chunks per (gb,d,s) lane. (unchanged)
// ---------------------------------------------------------------------------
__global__ __launch_bounds__(256) void scanCombine(
    const float* __restrict__ Aprod, const float* __restrict__ Hend,
    float* __restrict__ Hinit)
{
    int idx = blockIdx.x * 256 + threadIdx.x;  // (gb*DI+d)*DS + s
    int s  = idx & 15;
    int gd = idx >> 4;
    size_t base = (size_t)gd * CH * DS + s;
    float h = 0.f;
    for (int c0 = 0; c0 < CH; c0 += 8) {
        float ap[8], e[8];
        #pragma unroll
        for (int j = 0; j < 8; j++) {
            size_t o = base + (size_t)(c0 + j) * DS;
            ap[j] = Aprod[o]; e[j] = Hend[o];
        }
        #pragma unroll
        for (int j = 0; j < 8; j++) {
            Hinit[base + (size_t)(c0 + j) * DS] = h;
            h = ap[j] * h + e[j];
        }
    }
}

// ---------------------------------------------------------------------------
// Scan phase B + FUSED out_proj. Recomputes conv+silu (xc) from XZ (no XCb),
// dbl from compact DBLc, dt recompute, replay with h_init, y -> LDS bf16
// hi/lo, per-wave 3xbf16 MFMA epilogue with on-the-fly Wout split.
// OUTMODE 0: write Pout as bf16 hi/lo pairs. OUTMODE 1: scatter fp32 to out.
// ---------------------------------------------------------------------------
template<int OUTMODE>
__global__ __launch_bounds__(512) void scanB_fused(
    const float* __restrict__ XZ, const float* __restrict__ DBLc,
    const float* __restrict__ cw, const float* __restrict__ cb,
    const float* __restrict__ A_log,
    const float* __restrict__ Wdt, const float* __restrict__ bdt,
    const float* __restrict__ Dp, const float* __restrict__ Hinit,
    const float* __restrict__ Wout,
    float* __restrict__ Cout, short* __restrict__ Ph, short* __restrict__ Pl,
    int step)
{
    __shared__ float dbl[CL][48];
    __shared__ short Ys_hi[CL * YSTR];
    __shared__ short Ys_lo[CL * YSTR];
    int blk = blockIdx.x;
    int c  = blk & (CH - 1);
    int gb = blk >> 6;
    int g  = gb >> 1;
    int lay = g * 2 + step;
    int d = threadIdx.x;
    int r0 = gb * L + c * CL;

    for (int id = threadIdx.x; id < CL * 48; id += 512) {
        int rr = id / 48, cc = id - rr * 48;
        dbl[rr][cc] = DBLc[(size_t)(r0 + rr) * 48 + cc];
    }

    // ---- recompute conv + silu (same math as scanA2) ----
    float4 w4 = *(const float4*)&cw[((size_t)lay * DI + d) * 4];
    float cbv = cb[(size_t)lay * DI + d];
    float xzv[CL + 3];
    #pragma unroll
    for (int j = 0; j < CL + 3; j++) {
        int lr = c * CL + j - 3;
        xzv[j] = (lr < 0) ? 0.f : XZ[(size_t)(gb * L + lr) * 1024 + d];
    }
    float xc[CL], zz[CL];
    #pragma unroll
    for (int tt = 0; tt < CL; tt++) {
        float v = cbv + w4.x * xzv[tt] + w4.y * xzv[tt + 1]
                      + w4.z * xzv[tt + 2] + w4.w * xzv[tt + 3];
        xc[tt] = silu_f(v);
    }
    #pragma unroll
    for (int tt = 0; tt < CL; tt++) zz[tt] = XZ[(size_t)(r0 + tt) * 1024 + 512 + d];

    float wdt[16];
    const float* wrow = Wdt + ((size_t)lay * DI + d) * DR;
    #pragma unroll
    for (int k = 0; k < 16; k += 4) {
        float4 v = *(const float4*)&wrow[k];
        wdt[k] = v.x; wdt[k + 1] = v.y; wdt[k + 2] = v.z; wdt[k + 3] = v.w;
    }
    float bias = bdt[(size_t)lay * DI + d];

    float a[DS], h[DS];
    const float* al = A_log + ((size_t)lay * DI + d) * DS;
    size_t base = ((size_t)(gb * DI + d) * CH + c) * DS;
    #pragma unroll
    for (int q = 0; q < 4; q++) {
        float4 hv = *(const float4*)&Hinit[base + q * 4];
        h[q*4] = hv.x; h[q*4+1] = hv.y; h[q*4+2] = hv.z; h[q*4+3] = hv.w;
    }
    #pragma unroll
    for (int s = 0; s < DS; s++) a[s] = -__expf(al[s]);
    float Dv = Dp[(size_t)lay * DI + d];
    __syncthreads();

    #pragma unroll
    for (int tt = 0; tt < CL; tt++) {
        float dtr = bias;
        #pragma unroll
        for (int k = 0; k < 16; k++) dtr += dbl[tt][k] * wdt[k];
        float dt = softplus_f(dtr);
        float dx = dt * xc[tt];
        float y = 0.f;
        #pragma unroll
        for (int s = 0; s < DS; s++) {
            float da = __expf(dt * a[s]);
            h[s] = da * h[s] + dx * dbl[tt][16 + s];
            y += h[s] * dbl[tt][32 + s];
        }
        y += xc[tt] * Dv;
        y *= silu_f(zz[tt]);
        unsigned short hs = f2bf(y);
        Ys_hi[tt * YSTR + d] = (short)hs;
        Ys_lo[tt * YSTR + d] = (short)f2bf(y - bf2f(hs));
    }
    __syncthreads();

    // ---- fused out_proj epilogue: 16 rows x 256 cols, K=512 ----
    const int lane = threadIdx.x & 63, wv = threadIdx.x >> 6;
    const int m = lane & 15, quad = lane >> 4;
    const float* Wog = Wout + (size_t)lay * DM * DI;

    #pragma unroll
    for (int q = 0; q < 2; q++) {
        const int coln = wv * 32 + q * 16 + m;
        const float* wrp = &Wog[(size_t)coln * DI];
        bh8 wh[16], wl[16];
        #pragma unroll
        for (int i = 0; i < 16; i++) {
            const float* p = wrp + i * 32 + quad * 8;
            split8(*(const float4*)p, *(const float4*)(p + 4), wh[i], wl[i]);
        }
        f4x acc = {};
        #pragma unroll
        for (int i = 0; i < 16; i++) {
            const int kk = i * 32 + quad * 8;
            bh8 ahv = *(bh8*)&Ys_hi[m * YSTR + kk];
            bh8 alv = *(bh8*)&Ys_lo[m * YSTR + kk];
            acc = MFMA16(ahv, wh[i], acc, 0, 0, 0);
            acc = MFMA16(ahv, wl[i], acc, 0, 0, 0);
            acc = MFMA16(alv, wh[i], acc, 0, 0, 0);
        }
        #pragma unroll
        for (int r = 0; r < 4; r++) {
            int tt = quad * 4 + r;
            int grow = r0 + tt;
            if (OUTMODE == 0) {
                size_t o = (size_t)grow * DM + coln;
                unsigned short hs = f2bf(acc[r]);
                Ph[o] = (short)hs;
                Pl[o] = (short)f2bf(acc[r] - bf2f(hs));
            } else {
                int b = (grow >> 10) & 1, l = grow & 1023;
                size_t dst = (g == 0)
                    ? ((size_t)(b * 1024 + l) * 512 + coln)
                    : ((size_t)(b * 1024 + (1023 - l)) * 512 + 256 + coln);
                Cout[dst] = acc[r];
            }
        }
    }
}

extern "C" void kernel_launch(void* const* d_in, const int* in_sizes, int n_in,
                              void* d_out, int out_size, void* d_ws, size_t ws_size,
                              hipStream_t stream)
{
    const float* x        = (const float*)d_in[0];
    const float* in_proj  = (const float*)d_in[1];
    const float* conv_w   = (const float*)d_in[2];
    const float* conv_b   = (const float*)d_in[3];
    const float* x_proj   = (const float*)d_in[4];
    const float* dt_proj  = (const float*)d_in[5];
    const float* dt_bias  = (const float*)d_in[6];
    const float* A_log    = (const float*)d_in[7];
    const float* Dp       = (const float*)d_in[8];
    const float* out_proj = (const float*)d_in[9];
    float* out = (float*)d_out;

    float* w = (float*)d_ws;
    size_t o = 0;
    float* XZ    = w + o; o += (size_t)RTOT * 1024;
    float* DBLc  = w + o; o += (size_t)RTOT * 48;
    float* Aprod = w + o; o += (size_t)G * BB * DI * CH * DS;
    float* Hend  = w + o; o += (size_t)G * BB * DI * CH * DS;
    float* Hinit = w + o; o += (size_t)G * BB * DI * CH * DS;
    short* Ph    = (short*)(w + o); o += (size_t)RTOT * DM / 2;
    short* Pl    = (short*)(w + o); o += (size_t)RTOT * DM / 2;
    (void)ws_size; (void)in_sizes; (void)n_in; (void)out_size;

    for (int step = 0; step < 2; step++) {
        // in_proj: 4096x1024, K=256, MFMA 3xbf16. 128x128 tiles -> 256 blocks.
        if (step == 0)
            mfma_inproj<1><<<dim3(8, 32), 256, 0, stream>>>(
                x, nullptr, nullptr, in_proj, 0, XZ);
        else
            mfma_inproj<0><<<dim3(8, 32), 256, 0, stream>>>(
                nullptr, Ph, Pl, in_proj, 1, XZ);

        // fused conv+silu + x_proj MFMA + dt + chunk scan: 256 blocks.
        scanA2<<<G * BB * CH, 512, 0, stream>>>(
            XZ, conv_w, conv_b, x_proj, A_log, dt_proj, dt_bias,
            DBLc, Aprod, Hend, step);

        scanCombine<<<(G * BB * DI * DS) / 256, 256, 0, stream>>>(Aprod, Hend, Hinit);

        if (step == 0)
            scanB_fused<0><<<G * BB * CH, 512, 0, stream>>>(
                XZ, DBLc, conv_w, conv_b, A_log, dt_proj, dt_bias, Dp, Hinit,
                out_proj, nullptr, Ph, Pl, 0);
        else
            scanB_fused<1><<<G * BB * CH, 512, 0, stream>>>(
                XZ, DBLc, conv_w, conv_b, A_log, dt_proj, dt_bias, Dp, Hinit,
                out_proj, out, nullptr, nullptr, 1);
    }
}

// Round 5
// 222.512 us; speedup vs baseline: 1.1420x; 1.0371x over previous
//
#include <hip/hip_runtime.h>
#include <math.h>

#define G 2
#define BB 2
#define L 1024
#define DM 256
#define DI 512
#define DS 16
#define DR 16
#define CH 64              // chunks per sequence
#define CL 16              // L / CH
#define RTOT (G*BB*L)      // 4096 rows per layer-step
#define YSTR 520           // Ys LDS row stride (shorts)
#define XSTR 520           // xc LDS row stride (shorts)

#define NWIN  (4 * 2 * DI * DM)   // in_proj elements (4 layers)
#define NWOUT (4 * DM * DI)       // out_proj elements
#define NWX   (4 * 48 * DI)       // x_proj elements (4 layers)

typedef short bh8 __attribute__((ext_vector_type(8)));
typedef float f4x __attribute__((ext_vector_type(4)));

#define MFMA16 __builtin_amdgcn_mfma_f32_16x16x32_bf16

__device__ __forceinline__ float silu_f(float x) { return x / (1.f + __expf(-x)); }
__device__ __forceinline__ float softplus_f(float x) {
    return (x > 20.f) ? x : __logf(1.f + __expf(x));
}

__device__ __forceinline__ unsigned short f2bf(float f) {
    unsigned u = __float_as_uint(f);
    unsigned r = u + 0x7FFFu + ((u >> 16) & 1u);
    return (unsigned short)(r >> 16);
}
__device__ __forceinline__ float bf2f(unsigned short s) {
    return __uint_as_float(((unsigned)s) << 16);
}
__device__ __forceinline__ void split4s(float4 v, short4& h, short4& l) {
    unsigned short s;
    s = f2bf(v.x); h.x = (short)s; l.x = (short)f2bf(v.x - bf2f(s));
    s = f2bf(v.y); h.y = (short)s; l.y = (short)f2bf(v.y - bf2f(s));
    s = f2bf(v.z); h.z = (short)s; l.z = (short)f2bf(v.z - bf2f(s));
    s = f2bf(v.w); h.w = (short)s; l.w = (short)f2bf(v.w - bf2f(s));
}

// ---------------------------------------------------------------------------
// in_proj MFMA GEMM (3xbf16). BM=128, BN=64, K=256. grid (16,32) = 512 blocks.
// AMAP 1 (step 0): A = x (fp32, g-dependent time reversal), B = fp32 in_proj
//   split per-tile on the fly; epilogue = grid-stride one-time conversion of
//   ALL weights (in_proj/out_proj/x_proj -> bf16 hi/lo) for later dispatches.
// AMAP 0 (step 1): A = Pout pre-split bf16 hi/lo, B = pre-split Wih/Wil.
// ---------------------------------------------------------------------------
template<int AMAP>
__global__ __launch_bounds__(256) void mfma_inproj(
    const float* __restrict__ Ax,
    const short* __restrict__ APh, const short* __restrict__ APl,
    const float* __restrict__ WinF,
    const short* __restrict__ Wh, const short* __restrict__ Wl,
    int step, float* __restrict__ C,
    const float* __restrict__ cvtA, short* __restrict__ cAh, short* __restrict__ cAl, int n4a,
    const float* __restrict__ cvtB, short* __restrict__ cBh, short* __restrict__ cBl, int n4b,
    const float* __restrict__ cvtC, short* __restrict__ cCh, short* __restrict__ cCl, int n4c)
{
    constexpr int BM = 128, Ktot = DM, Nout = 2 * DI, ldc = 1024;
    __shared__ short As_hi[BM * 40];
    __shared__ short As_lo[BM * 40];
    __shared__ short Bs_hi[64 * 40];
    __shared__ short Bs_lo[64 * 40];

    const int row0 = blockIdx.y * BM;
    const int col0 = blockIdx.x * 64;
    const int g    = row0 >> 11;
    const int lay  = g * 2 + step;
    const short* Whg = Wh  + (size_t)lay * Nout * Ktot;
    const short* Wlg = Wl  + (size_t)lay * Nout * Ktot;
    const float* WFg = WinF + (size_t)lay * Nout * Ktot;
    const int t    = threadIdx.x;
    const int lane = t & 63, wv = t >> 6;
    const int m = lane & 15, quad = lane >> 4;
    const int wr = wv >> 1, wc = wv & 1;
    const int NT = Ktot / 32;     // 8

    float4 pa[4];
    short4 pah[4], pal[4], pbh[2], pbl[2];
    float4 pbf[2];
    auto loadT = [&](int kt) {
        const int kb = kt * 32;
        #pragma unroll
        for (int i = 0; i < 4; i++) {
            int id = t + 256 * i;
            int row = id >> 3, kq = id & 7;
            if (AMAP == 1) {
                int gr = row0 + row;
                int gg = gr >> 11, b = (gr >> 10) & 1, l = gr & 1023;
                int sl = gg ? (1023 - l) : l;
                pa[i] = *(const float4*)&Ax[(size_t)(b * 1024 + sl) * Ktot + kb + kq * 4];
            } else {
                size_t o = (size_t)(row0 + row) * Ktot + kb + kq * 4;
                pah[i] = *(const short4*)&APh[o];
                pal[i] = *(const short4*)&APl[o];
            }
        }
        #pragma unroll
        for (int i = 0; i < 2; i++) {
            int id = t + 256 * i;
            int row = id >> 3, kq = id & 7;
            if (AMAP == 1) {
                pbf[i] = *(const float4*)&WFg[(size_t)(col0 + row) * Ktot + kb + kq * 4];
            } else {
                size_t o = (size_t)(col0 + row) * Ktot + kb + kq * 4;
                pbh[i] = *(const short4*)&Whg[o];
                pbl[i] = *(const short4*)&Wlg[o];
            }
        }
    };

    f4x acc[4][2] = {};
    loadT(0);

    for (int kt = 0; kt < NT; kt++) {
        #pragma unroll
        for (int i = 0; i < 4; i++) {
            int id = t + 256 * i;
            int row = id >> 3, kq = id & 7;
            if (AMAP == 1) {
                short4 h4, l4; split4s(pa[i], h4, l4);
                *(short4*)&As_hi[row * 40 + kq * 4] = h4;
                *(short4*)&As_lo[row * 40 + kq * 4] = l4;
            } else {
                *(short4*)&As_hi[row * 40 + kq * 4] = pah[i];
                *(short4*)&As_lo[row * 40 + kq * 4] = pal[i];
            }
        }
        #pragma unroll
        for (int i = 0; i < 2; i++) {
            int id = t + 256 * i;
            int row = id >> 3, kq = id & 7;
            if (AMAP == 1) {
                short4 h4, l4; split4s(pbf[i], h4, l4);
                *(short4*)&Bs_hi[row * 40 + kq * 4] = h4;
                *(short4*)&Bs_lo[row * 40 + kq * 4] = l4;
            } else {
                *(short4*)&Bs_hi[row * 40 + kq * 4] = pbh[i];
                *(short4*)&Bs_lo[row * 40 + kq * 4] = pbl[i];
            }
        }
        __syncthreads();
        if (kt + 1 < NT) loadT(kt + 1);

        bh8 ah[4], al[4], bh[2], bl[2];
        #pragma unroll
        for (int p = 0; p < 4; p++) {
            int r = wr * 64 + p * 16 + m;
            ah[p] = *(bh8*)&As_hi[r * 40 + quad * 8];
            al[p] = *(bh8*)&As_lo[r * 40 + quad * 8];
        }
        #pragma unroll
        for (int q = 0; q < 2; q++) {
            int r = wc * 32 + q * 16 + m;
            bh[q] = *(bh8*)&Bs_hi[r * 40 + quad * 8];
            bl[q] = *(bh8*)&Bs_lo[r * 40 + quad * 8];
        }
        #pragma unroll
        for (int p = 0; p < 4; p++)
            #pragma unroll
            for (int q = 0; q < 2; q++) {
                acc[p][q] = MFMA16(ah[p], bh[q], acc[p][q], 0, 0, 0);
                acc[p][q] = MFMA16(ah[p], bl[q], acc[p][q], 0, 0, 0);
                acc[p][q] = MFMA16(al[p], bh[q], acc[p][q], 0, 0, 0);
            }
        __syncthreads();
    }

    #pragma unroll
    for (int p = 0; p < 4; p++)
        #pragma unroll
        for (int q = 0; q < 2; q++) {
            int gcol = col0 + wc * 32 + q * 16 + m;
            #pragma unroll
            for (int r = 0; r < 4; r++) {
                int grow = row0 + wr * 64 + p * 16 + quad * 4 + r;
                C[(size_t)grow * ldc + gcol] = acc[p][q][r];
            }
        }

    // ---- folded one-time weight conversion (step 0 only) ----
    if (AMAP == 1) {
        const int bid = blockIdx.y * 16 + blockIdx.x;      // 0..511
        const int ntot = n4a + n4b + n4c;
        for (int i = bid * 256 + t; i < ntot; i += 512 * 256) {
            int j = i; const float* W; short *H, *Lo;
            if (j < n4a) { W = cvtA; H = cAh; Lo = cAl; }
            else if (j < n4a + n4b) { j -= n4a; W = cvtB; H = cBh; Lo = cBl; }
            else { j -= n4a + n4b; W = cvtC; H = cCh; Lo = cCl; }
            float4 v = *(const float4*)&W[(size_t)j * 4];
            short4 h4, l4; split4s(v, h4, l4);
            *(short4*)&H[(size_t)j * 4] = h4;
            *(short4*)&Lo[(size_t)j * 4] = l4;
        }
    }
}

// ---------------------------------------------------------------------------
// scanA2: conv+silu + x_proj GEMM (3xbf16 MFMA, split-K over 8 waves) + dt +
// chunk-local scan, one block per (gb, chunk). Pre-split Wxh/Wxl.
// Writes XCb (for scanB), DBLc (for scanB), Aprod/Hend (combine).
// ---------------------------------------------------------------------------
__global__ __launch_bounds__(512) void scanA2(
    const float* __restrict__ XZ, const float* __restrict__ cw,
    const float* __restrict__ cb,
    const short* __restrict__ Wxh, const short* __restrict__ Wxl,
    const float* __restrict__ A_log, const float* __restrict__ Wdt,
    const float* __restrict__ bdt,
    float* __restrict__ XCb, float* __restrict__ DBLc,
    float* __restrict__ Aprod, float* __restrict__ Hend, int step)
{
    __shared__ short xcH[CL * XSTR];
    __shared__ short xcL[CL * XSTR];
    __shared__ float part[8][CL][48];
    __shared__ float dbl[CL][48];

    const int blk = blockIdx.x;
    const int c  = blk & (CH - 1);
    const int gb = blk >> 6;
    const int g  = gb >> 1;
    const int lay = g * 2 + step;
    const int d  = threadIdx.x;          // channel 0..511
    const int r0 = gb * L + c * CL;

    // ---- depthwise conv + silu for channel d, rows r0..r0+CL-1 ----
    float4 w4 = *(const float4*)&cw[((size_t)lay * DI + d) * 4];
    float cbv = cb[(size_t)lay * DI + d];
    float xz[CL + 3];
    #pragma unroll
    for (int j = 0; j < CL + 3; j++) {
        int lr = c * CL + j - 3;                  // local row in sequence
        xz[j] = (lr < 0) ? 0.f : XZ[(size_t)(gb * L + lr) * 1024 + d];
    }
    float xc[CL];
    #pragma unroll
    for (int tt = 0; tt < CL; tt++) {
        float v = cbv + w4.x * xz[tt] + w4.y * xz[tt + 1]
                      + w4.z * xz[tt + 2] + w4.w * xz[tt + 3];
        v = silu_f(v);
        xc[tt] = v;
        XCb[(size_t)(r0 + tt) * DI + d] = v;      // side product for scanB
        unsigned short hs = f2bf(v);
        xcH[tt * XSTR + d] = (short)hs;
        xcL[tt * XSTR + d] = (short)f2bf(v - bf2f(hs));
    }
    __syncthreads();

    // ---- dbl[16][48] = xc[16][512] @ Wx^T : 3xbf16 MFMA, split-K=64/wave ----
    {
        const int lane = d & 63, wv = d >> 6;
        const int m = lane & 15, quad = lane >> 4;
        const int ks = wv * 64;
        const size_t wb = (size_t)lay * 48 * DI;
        f4x acc3[3] = {};
        #pragma unroll
        for (int kt = 0; kt < 2; kt++) {
            const int kb = ks + kt * 32 + quad * 8;
            bh8 ah = *(bh8*)&xcH[m * XSTR + kb];
            bh8 al = *(bh8*)&xcL[m * XSTR + kb];
            #pragma unroll
            for (int f = 0; f < 3; f++) {
                bh8 bh = *(const bh8*)&Wxh[wb + (size_t)(f * 16 + m) * DI + kb];
                bh8 bl = *(const bh8*)&Wxl[wb + (size_t)(f * 16 + m) * DI + kb];
                acc3[f] = MFMA16(ah, bh, acc3[f], 0, 0, 0);
                acc3[f] = MFMA16(ah, bl, acc3[f], 0, 0, 0);
                acc3[f] = MFMA16(al, bh, acc3[f], 0, 0, 0);
            }
        }
        #pragma unroll
        for (int f = 0; f < 3; f++)
            #pragma unroll
            for (int r = 0; r < 4; r++)
                part[wv][quad * 4 + r][f * 16 + m] = acc3[f][r];
    }
    __syncthreads();

    for (int o = d; o < CL * 48; o += 512) {
        int tt = o / 48, cc = o - tt * 48;
        float v = 0.f;
        #pragma unroll
        for (int w = 0; w < 8; w++) v += part[w][tt][cc];
        dbl[tt][cc] = v;
        DBLc[(size_t)(r0 + tt) * 48 + cc] = v;    // compact side-write for scanB
    }

    // ---- dt + chunk-local scan ----
    float wdt[16];
    const float* wrow = Wdt + ((size_t)lay * DI + d) * DR;
    #pragma unroll
    for (int k = 0; k < 16; k += 4) {
        float4 v = *(const float4*)&wrow[k];
        wdt[k] = v.x; wdt[k + 1] = v.y; wdt[k + 2] = v.z; wdt[k + 3] = v.w;
    }
    float bias = bdt[(size_t)lay * DI + d];

    float a[DS], h[DS], ap[DS];
    const float* al = A_log + ((size_t)lay * DI + d) * DS;
    #pragma unroll
    for (int s = 0; s < DS; s++) { a[s] = -__expf(al[s]); h[s] = 0.f; ap[s] = 1.f; }
    __syncthreads();

    for (int tt = 0; tt < CL; tt++) {
        float dtr = bias;
        #pragma unroll
        for (int k = 0; k < 16; k++) dtr += dbl[tt][k] * wdt[k];
        float dt = softplus_f(dtr);
        float dx = dt * xc[tt];
        #pragma unroll
        for (int s = 0; s < DS; s++) {
            float da = __expf(dt * a[s]);
            h[s] = da * h[s] + dx * dbl[tt][16 + s];
            ap[s] *= da;
        }
    }
    size_t base = ((size_t)(gb * DI + d) * CH + c) * DS;
    #pragma unroll
    for (int q = 0; q < 4; q++) {
        *(float4*)&Aprod[base + q * 4] = make_float4(ap[q*4], ap[q*4+1], ap[q*4+2], ap[q*4+3]);
        *(float4*)&Hend [base + q * 4] = make_float4(h[q*4],  h[q*4+1],  h[q*4+2],  h[q*4+3]);
    }
}

// ---------------------------------------------------------------------------
// Combine: serial exclusive scan over CH chunks per (gb,d,s) lane. (unchanged)
// ---------------------------------------------------------------------------
__global__ __launch_bounds__(256) void scanCombine(
    const float* __restrict__ Aprod, const float* __restrict__ Hend,
    float* __restrict__ Hinit)
{
    int idx = blockIdx.x * 256 + threadIdx.x;  // (gb*DI+d)*DS + s
    int s  = idx & 15;
    int gd = idx >> 4;
    size_t base = (size_t)gd * CH * DS + s;
    float h = 0.f;
    for (int c0 = 0; c0 < CH; c0 += 8) {
        float ap[8], e[8];
        #pragma unroll
        for (int j = 0; j < 8; j++) {
            size_t o = base + (size_t)(c0 + j) * DS;
            ap[j] = Aprod[o]; e[j] = Hend[o];
        }
        #pragma unroll
        for (int j = 0; j < 8; j++) {
            Hinit[base + (size_t)(c0 + j) * DS] = h;
            h = ap[j] * h + e[j];
        }
    }
}

// ---------------------------------------------------------------------------
// Scan phase B + FUSED out_proj: dbl from compact DBLc, xc from XCb, replay
// with h_init, y -> LDS (bf16 hi/lo), per-wave 3xbf16 MFMA epilogue with
// register-preloaded pre-split weight rows.
// OUTMODE 0: write Pout as bf16 hi/lo pairs. OUTMODE 1: scatter fp32 to out.
// ---------------------------------------------------------------------------
template<int OUTMODE>
__global__ __launch_bounds__(512) void scanB_fused(
    const float* __restrict__ XCb, const float* __restrict__ DBLc,
    const float* __restrict__ XZ, const float* __restrict__ A_log,
    const float* __restrict__ Wdt, const float* __restrict__ bdt,
    const float* __restrict__ Dp, const float* __restrict__ Hinit,
    const short* __restrict__ Woh, const short* __restrict__ Wol,
    float* __restrict__ Cout, short* __restrict__ Ph, short* __restrict__ Pl,
    int step)
{
    __shared__ float dbl[CL][48];
    __shared__ short Ys_hi[CL * YSTR];
    __shared__ short Ys_lo[CL * YSTR];
    int blk = blockIdx.x;
    int c  = blk & (CH - 1);
    int gb = blk >> 6;
    int g  = gb >> 1;
    int lay = g * 2 + step;
    int d = threadIdx.x;
    int r0 = gb * L + c * CL;

    for (int id = threadIdx.x; id < CL * 48; id += 512) {
        int rr = id / 48, cc = id - rr * 48;
        dbl[rr][cc] = DBLc[(size_t)(r0 + rr) * 48 + cc];
    }

    float xc[CL], zz[CL];
    #pragma unroll
    for (int tt = 0; tt < CL; tt++) xc[tt] = XCb[(size_t)(r0 + tt) * DI + d];
    #pragma unroll
    for (int tt = 0; tt < CL; tt++) zz[tt] = XZ[(size_t)(r0 + tt) * 1024 + 512 + d];

    float wdt[16];
    const float* wrow = Wdt + ((size_t)lay * DI + d) * DR;
    #pragma unroll
    for (int k = 0; k < 16; k += 4) {
        float4 v = *(const float4*)&wrow[k];
        wdt[k] = v.x; wdt[k + 1] = v.y; wdt[k + 2] = v.z; wdt[k + 3] = v.w;
    }
    float bias = bdt[(size_t)lay * DI + d];

    float a[DS], h[DS];
    const float* al = A_log + ((size_t)lay * DI + d) * DS;
    size_t base = ((size_t)(gb * DI + d) * CH + c) * DS;
    #pragma unroll
    for (int q = 0; q < 4; q++) {
        float4 hv = *(const float4*)&Hinit[base + q * 4];
        h[q*4] = hv.x; h[q*4+1] = hv.y; h[q*4+2] = hv.z; h[q*4+3] = hv.w;
    }
    #pragma unroll
    for (int s = 0; s < DS; s++) a[s] = -__expf(al[s]);
    float Dv = Dp[(size_t)lay * DI + d];
    __syncthreads();

    #pragma unroll
    for (int tt = 0; tt < CL; tt++) {
        float dtr = bias;
        #pragma unroll
        for (int k = 0; k < 16; k++) dtr += dbl[tt][k] * wdt[k];
        float dt = softplus_f(dtr);
        float dx = dt * xc[tt];
        float y = 0.f;
        #pragma unroll
        for (int s = 0; s < DS; s++) {
            float da = __expf(dt * a[s]);
            h[s] = da * h[s] + dx * dbl[tt][16 + s];
            y += h[s] * dbl[tt][32 + s];
        }
        y += xc[tt] * Dv;
        y *= silu_f(zz[tt]);
        unsigned short hs = f2bf(y);
        Ys_hi[tt * YSTR + d] = (short)hs;
        Ys_lo[tt * YSTR + d] = (short)f2bf(y - bf2f(hs));
    }
    __syncthreads();

    // ---- fused out_proj epilogue: 16 rows x 256 cols, K=512 ----
    const int lane = threadIdx.x & 63, wv = threadIdx.x >> 6;
    const int m = lane & 15, quad = lane >> 4;
    const size_t wbase = (size_t)lay * DM * DI;

    #pragma unroll
    for (int q = 0; q < 2; q++) {
        const int coln = wv * 32 + q * 16 + m;
        const size_t wrow2 = wbase + (size_t)coln * DI;
        bh8 wh[16], wl[16];
        #pragma unroll
        for (int i = 0; i < 16; i++) {
            const int kk = i * 32 + quad * 8;
            wh[i] = *(const bh8*)&Woh[wrow2 + kk];
            wl[i] = *(const bh8*)&Wol[wrow2 + kk];
        }
        f4x acc = {};
        #pragma unroll
        for (int i = 0; i < 16; i++) {
            const int kk = i * 32 + quad * 8;
            bh8 ahv = *(bh8*)&Ys_hi[m * YSTR + kk];
            bh8 alv = *(bh8*)&Ys_lo[m * YSTR + kk];
            acc = MFMA16(ahv, wh[i], acc, 0, 0, 0);
            acc = MFMA16(ahv, wl[i], acc, 0, 0, 0);
            acc = MFMA16(alv, wh[i], acc, 0, 0, 0);
        }
        #pragma unroll
        for (int r = 0; r < 4; r++) {
            int tt = quad * 4 + r;
            int grow = r0 + tt;
            if (OUTMODE == 0) {
                size_t o = (size_t)grow * DM + coln;
                unsigned short hs = f2bf(acc[r]);
                Ph[o] = (short)hs;
                Pl[o] = (short)f2bf(acc[r] - bf2f(hs));
            } else {
                int b = (grow >> 10) & 1, l = grow & 1023;
                size_t dst = (g == 0)
                    ? ((size_t)(b * 1024 + l) * 512 + coln)
                    : ((size_t)(b * 1024 + (1023 - l)) * 512 + 256 + coln);
                Cout[dst] = acc[r];
            }
        }
    }
}

extern "C" void kernel_launch(void* const* d_in, const int* in_sizes, int n_in,
                              void* d_out, int out_size, void* d_ws, size_t ws_size,
                              hipStream_t stream)
{
    const float* x        = (const float*)d_in[0];
    const float* in_proj  = (const float*)d_in[1];
    const float* conv_w   = (const float*)d_in[2];
    const float* conv_b   = (const float*)d_in[3];
    const float* x_proj   = (const float*)d_in[4];
    const float* dt_proj  = (const float*)d_in[5];
    const float* dt_bias  = (const float*)d_in[6];
    const float* A_log    = (const float*)d_in[7];
    const float* Dp       = (const float*)d_in[8];
    const float* out_proj = (const float*)d_in[9];
    float* out = (float*)d_out;

    float* w = (float*)d_ws;
    size_t o = 0;
    float* XZ    = w + o; o += (size_t)RTOT * 1024;
    float* XCb   = w + o; o += (size_t)RTOT * DI;
    float* DBLc  = w + o; o += (size_t)RTOT * 48;
    float* Aprod = w + o; o += (size_t)G * BB * DI * CH * DS;
    float* Hend  = w + o; o += (size_t)G * BB * DI * CH * DS;
    float* Hinit = w + o; o += (size_t)G * BB * DI * CH * DS;
    short* Wih   = (short*)(w + o); o += NWIN / 2;
    short* Wil   = (short*)(w + o); o += NWIN / 2;
    short* Woh   = (short*)(w + o); o += NWOUT / 2;
    short* Wol   = (short*)(w + o); o += NWOUT / 2;
    short* Wxh   = (short*)(w + o); o += NWX / 2;
    short* Wxl   = (short*)(w + o); o += NWX / 2;
    short* Ph    = (short*)(w + o); o += (size_t)RTOT * DM / 2;
    short* Pl    = (short*)(w + o); o += (size_t)RTOT * DM / 2;
    (void)ws_size; (void)in_sizes; (void)n_in; (void)out_size;

    for (int step = 0; step < 2; step++) {
        // in_proj: 4096x1024, K=256, MFMA 3xbf16. 128x64 tiles -> 512 blocks.
        // Step 0 additionally performs the one-time weight pre-split epilogue.
        if (step == 0)
            mfma_inproj<1><<<dim3(16, 32), 256, 0, stream>>>(
                x, nullptr, nullptr, in_proj, nullptr, nullptr, 0, XZ,
                in_proj, Wih, Wil, NWIN / 4,
                out_proj, Woh, Wol, NWOUT / 4,
                x_proj, Wxh, Wxl, NWX / 4);
        else
            mfma_inproj<0><<<dim3(16, 32), 256, 0, stream>>>(
                nullptr, Ph, Pl, nullptr, Wih, Wil, 1, XZ,
                nullptr, nullptr, nullptr, 0,
                nullptr, nullptr, nullptr, 0,
                nullptr, nullptr, nullptr, 0);

        // fused conv+silu + x_proj MFMA + dt + chunk scan: 256 blocks.
        scanA2<<<G * BB * CH, 512, 0, stream>>>(
            XZ, conv_w, conv_b, Wxh, Wxl, A_log, dt_proj, dt_bias,
            XCb, DBLc, Aprod, Hend, step);

        scanCombine<<<(G * BB * DI * DS) / 256, 256, 0, stream>>>(Aprod, Hend, Hinit);

        if (step == 0)
            scanB_fused<0><<<G * BB * CH, 512, 0, stream>>>(
                XCb, DBLc, XZ, A_log, dt_proj, dt_bias, Dp, Hinit,
                Woh, Wol, nullptr, Ph, Pl, 0);
        else
            scanB_fused<1><<<G * BB * CH, 512, 0, stream>>>(
                XCb, DBLc, XZ, A_log, dt_proj, dt_bias, Dp, Hinit,
                Woh, Wol, out, nullptr, nullptr, 1);
    }
}